// Round 2
// baseline (210.800 us; speedup 1.0000x reference)
//
#include <hip/hip_runtime.h>

// ---------------- fixed problem geometry (validated by out_size) -------------
#define NBATCH   8
#define TT       8
#define NPTS     6890
#define KCLS     7
#define CCH      128
#define BSAMP    64            // NBATCH*TT
#define NOUT     1722          // n = NPTS/4
#define DSUM     512
#define PCADIM   64
#define V3       23106         // 7702*3
#define EPSBN    1e-5f

#define NW       108           // ceil(NPTS/64) mask words per sample
#define PCHUNK   128           // points per k2 block
#define NCHUNK   54            // ceil(NPTS/PCHUNK)
#define ZROWS    8             // gf rows zeroed per kz block
#define NZBLK    216           // ceil(NOUT/ZROWS)

// output layout (flat f32)
#define OFF_GV     0
#define OFF_GF     (BSAMP * NOUT * 3)                 // 330624
#define OFF_COEFF  (OFF_GF + BSAMP * NOUT * CCH)      // 14437248
#define OFF_TPOSE  (OFF_COEFF + NBATCH * PCADIM)      // 14437760

// ---------------- kernel 0: per-point argmax -> selection bitmask ------------
__global__ __launch_bounds__(256) void k0_mask(
    const float* __restrict__ logits,    // [BSAMP, NPTS, KCLS]
    const int*   __restrict__ d_label,
    unsigned long long* __restrict__ ws_mask)  // [BSAMP, NW]
{
    const int b     = blockIdx.x / 27;
    const int chunk = blockIdx.x % 27;
    const int tid   = threadIdx.x;
    const int i     = chunk * 256 + tid;
    const int label = d_label[0];

    bool sel = false;
    if (i < NPTS) {
        const float* p = logits + ((size_t)b * NPTS + i) * KCLS;
        float best = p[0]; int bi = 0;
        #pragma unroll
        for (int k = 1; k < KCLS; ++k) {
            float v = p[k];
            if (v > best) { best = v; bi = k; }
        }
        sel = (bi == label);
    }
    const unsigned long long m = __ballot(sel);
    if ((tid & 63) == 0) {
        const int w = chunk * 4 + (tid >> 6);
        if (w < NW) ws_mask[b * NW + w] = m;
    }
}

// ---------------- kernel 1: per-sample scan -> pos array, gv gather ----------
__global__ __launch_bounds__(256) void k1_scan(
    const float* __restrict__ x,         // [BSAMP, NPTS, 3]
    const unsigned long long* __restrict__ ws_mask,
    float*       __restrict__ gv,        // [BSAMP, NOUT, 3]
    int*         __restrict__ ws_pos,    // [BSAMP, NPTS]
    int*         __restrict__ ws_count)  // [BSAMP]
{
    const int b   = blockIdx.x;
    const int tid = threadIdx.x;

    __shared__ unsigned long long smask[NW];
    __shared__ int spref[NW + 1];

    if (tid < NW) smask[tid] = ws_mask[b * NW + tid];
    __syncthreads();

    if (tid == 0) {
        int run = 0;
        for (int w = 0; w < NW; ++w) { spref[w] = run; run += __popcll(smask[w]); }
        spref[NW] = run;
        ws_count[b] = run < NOUT ? run : NOUT;
    }
    __syncthreads();

    const float* xb = x + (size_t)b * NPTS * 3;
    for (int i = tid; i < NPTS; i += 256) {
        const int w = i >> 6, lb = i & 63;
        const unsigned long long m = smask[w];
        const bool sel = (m >> lb) & 1ull;
        int pos = spref[w] + __popcll(m & ((1ull << lb) - 1ull));
        int p = (sel && pos < NOUT) ? pos : -1;
        ws_pos[b * NPTS + i] = p;
        if (p >= 0) {
            const size_t go = ((size_t)b * NOUT + p) * 3;
            gv[go + 0] = xb[(size_t)i * 3 + 0];
            gv[go + 1] = xb[(size_t)i * 3 + 1];
            gv[go + 2] = xb[(size_t)i * 3 + 2];
        }
    }

    int cnt = spref[NW]; if (cnt > NOUT) cnt = NOUT;
    for (int j = cnt + tid; j < NOUT; j += 256) {
        const size_t go = ((size_t)b * NOUT + j) * 3;
        gv[go + 0] = 0.f; gv[go + 1] = 0.f; gv[go + 2] = 0.f;
    }
}

// ---------------- kernel 2: coalesced feature read -> LDS transpose ----------
__global__ __launch_bounds__(256) void k2_gather(
    const float* __restrict__ feature,   // [BSAMP, CCH, NPTS]
    const int*   __restrict__ ws_pos,
    float*       __restrict__ gf)        // [BSAMP, NOUT, CCH]
{
    __shared__ float ldsT[PCHUNK * (CCH + 1)];   // [point][channel], pad 129
    __shared__ int   spos[PCHUNK];
    __shared__ int   sel_list[PCHUNK];
    __shared__ int   nsel_cnt;

    const int b     = blockIdx.x / NCHUNK;
    const int chunk = blockIdx.x % NCHUNK;
    const int i0    = chunk * PCHUNK;
    const int tid   = threadIdx.x;
    const int ilim  = min(PCHUNK, NPTS - i0);    // 128 or 106 (even)

    // phase A: coalesced float2 load of feature[b, :, i0:i0+PCHUNK] + transpose
    const float* fb = feature + (size_t)b * CCH * NPTS;
    const int col = (tid & 63) * 2;              // even
    const int cbase = tid >> 6;
    #pragma unroll 4
    for (int it = 0; it < 32; ++it) {
        const int c = it * 4 + cbase;
        float2 v = make_float2(0.f, 0.f);
        if (col < ilim) v = *(const float2*)(fb + (size_t)c * NPTS + i0 + col);
        ldsT[col * (CCH + 1) + c]       = v.x;
        ldsT[(col + 1) * (CCH + 1) + c] = v.y;
    }

    if (tid == 0) nsel_cnt = 0;
    if (tid < PCHUNK) spos[tid] = (tid < ilim) ? ws_pos[b * NPTS + i0 + tid] : -1;
    __syncthreads();
    if (tid < ilim && spos[tid] >= 0) {
        const int slot = atomicAdd(&nsel_cnt, 1);
        sel_list[slot] = tid;
    }
    __syncthreads();

    // phase B: coalesced 512B row writes for selected points
    const int nsel = nsel_cnt;
    const int c = tid & 127;
    for (int s = (tid >> 7); s < nsel; s += 2) {
        const int p = sel_list[s];
        const int pos = spos[p];
        gf[((size_t)b * NOUT + pos) * CCH + c] = ldsT[p * (CCH + 1) + c];
    }
}

// ---------------- kernel z: zero tail rows of gf -----------------------------
__global__ __launch_bounds__(256) void kz_zero(
    const int* __restrict__ ws_count,
    float*     __restrict__ gf)
{
    const int b  = blockIdx.x / NZBLK;
    const int jb = blockIdx.x % NZBLK;
    const int tid = threadIdx.x;
    const int j = jb * ZROWS + (tid >> 5);
    const int cnt = ws_count[b];
    if (j >= NOUT || j < cnt) return;
    float4* row = (float4*)(gf + ((size_t)b * NOUT + j) * CCH);
    row[tid & 31] = make_float4(0.f, 0.f, 0.f, 0.f);
}

// ---------------- kernel 3: max over T + 3-layer MLP (wave-coop dots) --------
__global__ __launch_bounds__(256) void k3_mlp(
    const float* __restrict__ gsum,      // [NBATCH, TT, DSUM]
    const float* __restrict__ W1, const float* __restrict__ b1,
    const float* __restrict__ g1, const float* __restrict__ be1,
    const float* __restrict__ rm1, const float* __restrict__ rv1,
    const float* __restrict__ W2, const float* __restrict__ b2,
    const float* __restrict__ g2, const float* __restrict__ be2,
    const float* __restrict__ rm2, const float* __restrict__ rv2,
    const float* __restrict__ W3, const float* __restrict__ b3,
    float* __restrict__ coeff_out,       // d_out + OFF_COEFF
    float* __restrict__ coeff_ws)
{
    const int b   = blockIdx.x;          // sample
    const int tid = threadIdx.x;
    const int lane = tid & 63;
    const int wv   = tid >> 6;

    __shared__ float gs[DSUM];
    __shared__ float h1[128];
    __shared__ float h2[64];

    for (int d = tid; d < DSUM; d += 256) {
        const float* p = gsum + ((size_t)b * TT) * DSUM + d;
        float m = p[0];
        #pragma unroll
        for (int t = 1; t < TT; ++t) m = fmaxf(m, p[(size_t)t * DSUM]);
        gs[d] = m;
    }
    __syncthreads();

    // layer 1: 128 outputs, dot length 512
    for (int r = 0; r < 32; ++r) {
        const int jj = wv * 32 + r;
        const float* w = W1 + (size_t)jj * DSUM;
        float p = 0.f;
        #pragma unroll
        for (int d = lane; d < DSUM; d += 64) p = fmaf(w[d], gs[d], p);
        #pragma unroll
        for (int off = 32; off; off >>= 1) p += __shfl_xor(p, off);
        if (lane == 0) {
            p += b1[jj];
            p = (p - rm1[jj]) * rsqrtf(rv1[jj] + EPSBN) * g1[jj] + be1[jj];
            h1[jj] = fmaxf(p, 0.f);
        }
    }
    __syncthreads();

    // layer 2: 64 outputs, dot length 128
    for (int r = 0; r < 16; ++r) {
        const int jj = wv * 16 + r;
        const float* w = W2 + (size_t)jj * 128;
        float p = fmaf(w[lane], h1[lane], 0.f) + w[lane + 64] * h1[lane + 64];
        #pragma unroll
        for (int off = 32; off; off >>= 1) p += __shfl_xor(p, off);
        if (lane == 0) {
            p += b2[jj];
            p = (p - rm2[jj]) * rsqrtf(rv2[jj] + EPSBN) * g2[jj] + be2[jj];
            h2[jj] = fmaxf(p, 0.f);
        }
    }
    __syncthreads();

    // layer 3: 64 outputs, dot length 64
    for (int r = 0; r < 16; ++r) {
        const int jj = wv * 16 + r;
        float p = W3[(size_t)jj * 64 + lane] * h2[lane];
        #pragma unroll
        for (int off = 32; off; off >>= 1) p += __shfl_xor(p, off);
        if (lane == 0) {
            p += b3[jj];
            coeff_out[b * PCADIM + jj] = p;
            coeff_ws[b * PCADIM + jj]  = p;
        }
    }
}

// ---------------- kernel 4: PCA inverse transform ----------------------------
__global__ __launch_bounds__(256) void k4_tpose(
    const float* __restrict__ coeff_ws,  // [NBATCH, PCADIM]
    const float* __restrict__ comp,      // [PCADIM, V3]
    const float* __restrict__ mean_,     // [V3]
    const float* __restrict__ scale_,    // [V3]
    float* __restrict__ tpose)           // [NBATCH, V3]
{
    __shared__ float sc[NBATCH * PCADIM];
    const int tid = threadIdx.x;
    for (int o = tid; o < NBATCH * PCADIM; o += 256) sc[o] = coeff_ws[o];
    __syncthreads();

    const int v = blockIdx.x * 256 + tid;
    if (v >= V3) return;

    float acc[NBATCH];
    #pragma unroll
    for (int s = 0; s < NBATCH; ++s) acc[s] = 0.f;

    for (int k = 0; k < PCADIM; ++k) {
        const float pv = comp[(size_t)k * V3 + v];
        #pragma unroll
        for (int s = 0; s < NBATCH; ++s)
            acc[s] = fmaf(sc[s * PCADIM + k], pv, acc[s]);
    }
    const float mn = mean_[v], scl = scale_[v];
    #pragma unroll
    for (int s = 0; s < NBATCH; ++s)
        tpose[(size_t)s * V3 + v] = (acc[s] + mn) * scl;
}

// ---------------- launcher ---------------------------------------------------
extern "C" void kernel_launch(void* const* d_in, const int* in_sizes, int n_in,
                              void* d_out, int out_size, void* d_ws, size_t ws_size,
                              hipStream_t stream) {
    const float* x      = (const float*)d_in[0];
    const float* logits = (const float*)d_in[1];
    const float* feat   = (const float*)d_in[2];
    const float* gsum   = (const float*)d_in[3];
    const float* W1  = (const float*)d_in[4];
    const float* b1  = (const float*)d_in[5];
    const float* g1  = (const float*)d_in[6];
    const float* be1 = (const float*)d_in[7];
    const float* rm1 = (const float*)d_in[8];
    const float* rv1 = (const float*)d_in[9];
    const float* W2  = (const float*)d_in[10];
    const float* b2  = (const float*)d_in[11];
    const float* g2  = (const float*)d_in[12];
    const float* be2 = (const float*)d_in[13];
    const float* rm2 = (const float*)d_in[14];
    const float* rv2 = (const float*)d_in[15];
    const float* W3  = (const float*)d_in[16];
    const float* b3  = (const float*)d_in[17];
    const float* comp  = (const float*)d_in[18];
    const float* mean_ = (const float*)d_in[19];
    const float* scale_= (const float*)d_in[20];
    const int* d_label = (const int*)d_in[21];

    float* out   = (float*)d_out;
    float* gv    = out + OFF_GV;
    float* gf    = out + OFF_GF;
    float* coeff = out + OFF_COEFF;
    float* tpose = out + OFF_TPOSE;

    unsigned long long* ws_mask = (unsigned long long*)d_ws;      // 64*108
    int*   ws_pos   = (int*)(ws_mask + BSAMP * NW);               // 64*6890
    int*   ws_count = ws_pos + BSAMP * NPTS;                      // 64
    float* coeff_ws = (float*)(ws_count + BSAMP);

    k0_mask <<<BSAMP * 27,      256, 0, stream>>>(logits, d_label, ws_mask);
    k1_scan <<<BSAMP,           256, 0, stream>>>(x, ws_mask, gv, ws_pos, ws_count);
    k2_gather<<<BSAMP * NCHUNK, 256, 0, stream>>>(feat, ws_pos, gf);
    kz_zero <<<BSAMP * NZBLK,   256, 0, stream>>>(ws_count, gf);
    k3_mlp  <<<NBATCH,          256, 0, stream>>>(gsum, W1, b1, g1, be1, rm1, rv1,
                                                  W2, b2, g2, be2, rm2, rv2, W3, b3,
                                                  coeff, coeff_ws);
    k4_tpose<<<(V3 + 255) / 256, 256, 0, stream>>>(coeff_ws, comp, mean_, scale_, tpose);
}

// Round 3
// 145.964 us; speedup vs baseline: 1.4442x; 1.4442x over previous
//
#include <hip/hip_runtime.h>

// ---------------- fixed problem geometry (validated by out_size) -------------
#define NBATCH   8
#define TT       8
#define NPTS     6890
#define KCLS     7
#define CCH      128
#define BSAMP    64            // NBATCH*TT
#define NOUT     1722          // n = NPTS/4
#define DSUM     512
#define PCADIM   64
#define V3       23106         // 7702*3
#define EPSBN    1e-5f

#define NW       108           // ceil(NPTS/64) mask words per sample
#define PCH      64            // points per k2 chunk
#define NCH      108           // ceil(NPTS/PCH); last chunk = 42 points (even)
#define LDSP     (CCH + 1)     // pad 129 -> both LDS phases 2-way (free)
#define ZROWS    8             // gf rows zeroed per kz block
#define NZBLK    216           // ceil(NOUT/ZROWS)

// output layout (flat f32)
#define OFF_GV     0
#define OFF_GF     (BSAMP * NOUT * 3)                 // 330624
#define OFF_COEFF  (OFF_GF + BSAMP * NOUT * CCH)      // 14437248
#define OFF_TPOSE  (OFF_COEFF + NBATCH * PCADIM)      // 14437760

// ---------------- kernel 0: per-point argmax -> selection bitmask ------------
__global__ __launch_bounds__(256) void k0_mask(
    const float* __restrict__ logits,    // [BSAMP, NPTS, KCLS]
    const int*   __restrict__ d_label,
    unsigned long long* __restrict__ ws_mask)  // [BSAMP, NW]
{
    const int b     = blockIdx.x / 27;
    const int chunk = blockIdx.x % 27;
    const int tid   = threadIdx.x;
    const int i     = chunk * 256 + tid;
    const int label = d_label[0];

    bool sel = false;
    if (i < NPTS) {
        const float* p = logits + ((size_t)b * NPTS + i) * KCLS;
        float best = p[0]; int bi = 0;
        #pragma unroll
        for (int k = 1; k < KCLS; ++k) {
            float v = p[k];
            if (v > best) { best = v; bi = k; }
        }
        sel = (bi == label);
    }
    const unsigned long long m = __ballot(sel);
    if ((tid & 63) == 0) {
        const int w = chunk * 4 + (tid >> 6);
        if (w < NW) ws_mask[b * NW + w] = m;
    }
}

// ---------------- kernel 1: per-sample scan -> pos array, gv gather ----------
__global__ __launch_bounds__(256) void k1_scan(
    const float* __restrict__ x,         // [BSAMP, NPTS, 3]
    const unsigned long long* __restrict__ ws_mask,
    float*       __restrict__ gv,        // [BSAMP, NOUT, 3]
    int*         __restrict__ ws_pos,    // [BSAMP, NPTS]
    int*         __restrict__ ws_count)  // [BSAMP]
{
    const int b   = blockIdx.x;
    const int tid = threadIdx.x;

    __shared__ unsigned long long smask[NW];
    __shared__ int spref[NW + 1];

    if (tid < NW) smask[tid] = ws_mask[b * NW + tid];
    __syncthreads();

    if (tid == 0) {
        int run = 0;
        for (int w = 0; w < NW; ++w) { spref[w] = run; run += __popcll(smask[w]); }
        spref[NW] = run;
        ws_count[b] = run < NOUT ? run : NOUT;
    }
    __syncthreads();

    const float* xb = x + (size_t)b * NPTS * 3;
    for (int i = tid; i < NPTS; i += 256) {
        const int w = i >> 6, lb = i & 63;
        const unsigned long long m = smask[w];
        const bool sel = (m >> lb) & 1ull;
        int pos = spref[w] + __popcll(m & ((1ull << lb) - 1ull));
        int p = (sel && pos < NOUT) ? pos : -1;
        ws_pos[b * NPTS + i] = p;
        if (p >= 0) {
            const size_t go = ((size_t)b * NOUT + p) * 3;
            gv[go + 0] = xb[(size_t)i * 3 + 0];
            gv[go + 1] = xb[(size_t)i * 3 + 1];
            gv[go + 2] = xb[(size_t)i * 3 + 2];
        }
    }

    int cnt = spref[NW]; if (cnt > NOUT) cnt = NOUT;
    for (int j = cnt + tid; j < NOUT; j += 256) {
        const size_t go = ((size_t)b * NOUT + j) * 3;
        gv[go + 0] = 0.f; gv[go + 1] = 0.f; gv[go + 2] = 0.f;
    }
}

// ---------------- kernel 2: reg-staged coalesced read -> LDS transpose -------
// 64-pt chunk: lane l loads points [2*(l&31), +1] for channels (l>>5)+8*it,
// it=0..15, ALL loads issued into regs before any LDS write (16 in flight).
__global__ __launch_bounds__(256) void k2_gather(
    const float* __restrict__ feature,   // [BSAMP, CCH, NPTS]
    const int*   __restrict__ ws_pos,
    float*       __restrict__ gf)        // [BSAMP, NOUT, CCH]
{
    __shared__ float lds[PCH * LDSP];    // 33024 B -> 4 blocks/CU
    __shared__ int   spos[PCH];
    __shared__ int   sel_list[PCH];
    __shared__ int   s_nsel;

    const int b     = blockIdx.x / NCH;
    const int chunk = blockIdx.x % NCH;
    const int i0    = chunk * PCH;
    const int tid   = threadIdx.x;
    const int ilim  = min(PCH, NPTS - i0);   // 64 or 42 (even)

    const int pt2 = tid & 31;            // float2 slot -> points 2*pt2, 2*pt2+1
    const int cg  = tid >> 5;            // 0..7
    const int p0  = pt2 * 2;

    // phase A1: issue all 16 global float2 loads into registers
    const float* fb = feature + (size_t)b * CCH * NPTS + i0 + p0;
    float2 r[16];
    if (p0 < ilim) {
        #pragma unroll
        for (int it = 0; it < 16; ++it) {
            const int c = cg + 8 * it;
            r[it] = *(const float2*)(fb + (size_t)c * NPTS);
        }
    } else {
        #pragma unroll
        for (int it = 0; it < 16; ++it) r[it] = make_float2(0.f, 0.f);
    }

    // selection list for this chunk (wave 0 only, ballot scan — no atomics)
    if (tid < 64) {
        const int sp = (tid < ilim) ? ws_pos[b * NPTS + i0 + tid] : -1;
        spos[tid] = sp;
        const unsigned long long m = __ballot(sp >= 0);
        const int before = __popcll(m & ((1ull << tid) - 1ull));
        if (sp >= 0) sel_list[before] = tid;
        if (tid == 0) s_nsel = __popcll(m);
    }

    // phase A2: LDS transpose writes (bank: 2*pt2+i+c mod 32 -> 2-way, free)
    #pragma unroll
    for (int it = 0; it < 16; ++it) {
        const int c = cg + 8 * it;
        lds[p0 * LDSP + c]       = r[it].x;
        lds[(p0 + 1) * LDSP + c] = r[it].y;
    }
    __syncthreads();

    // phase B: coalesced 512B row writes for selected points
    const int nsel = s_nsel;
    const int c = tid & 127;
    for (int s = tid >> 7; s < nsel; s += 2) {
        const int p = sel_list[s];
        gf[((size_t)b * NOUT + spos[p]) * CCH + c] = lds[p * LDSP + c];
    }
}

// ---------------- kernel z: zero tail rows of gf -----------------------------
__global__ __launch_bounds__(256) void kz_zero(
    const int* __restrict__ ws_count,
    float*     __restrict__ gf)
{
    const int b  = blockIdx.x / NZBLK;
    const int jb = blockIdx.x % NZBLK;
    const int tid = threadIdx.x;
    const int j = jb * ZROWS + (tid >> 5);
    const int cnt = ws_count[b];
    if (j >= NOUT || j < cnt) return;
    float4* row = (float4*)(gf + ((size_t)b * NOUT + j) * CCH);
    row[tid & 31] = make_float4(0.f, 0.f, 0.f, 0.f);
}

// ---------------- kernel 3: max over T + 3-layer MLP (wave-coop dots) --------
__global__ __launch_bounds__(256) void k3_mlp(
    const float* __restrict__ gsum,      // [NBATCH, TT, DSUM]
    const float* __restrict__ W1, const float* __restrict__ b1,
    const float* __restrict__ g1, const float* __restrict__ be1,
    const float* __restrict__ rm1, const float* __restrict__ rv1,
    const float* __restrict__ W2, const float* __restrict__ b2,
    const float* __restrict__ g2, const float* __restrict__ be2,
    const float* __restrict__ rm2, const float* __restrict__ rv2,
    const float* __restrict__ W3, const float* __restrict__ b3,
    float* __restrict__ coeff_out,       // d_out + OFF_COEFF
    float* __restrict__ coeff_ws)
{
    const int b   = blockIdx.x;          // sample
    const int tid = threadIdx.x;
    const int lane = tid & 63;
    const int wv   = tid >> 6;

    __shared__ float gs[DSUM];
    __shared__ float h1[128];
    __shared__ float h2[64];

    for (int d = tid; d < DSUM; d += 256) {
        const float* p = gsum + ((size_t)b * TT) * DSUM + d;
        float m = p[0];
        #pragma unroll
        for (int t = 1; t < TT; ++t) m = fmaxf(m, p[(size_t)t * DSUM]);
        gs[d] = m;
    }
    __syncthreads();

    // layer 1: 128 outputs, dot length 512
    for (int r = 0; r < 32; ++r) {
        const int jj = wv * 32 + r;
        const float* w = W1 + (size_t)jj * DSUM;
        float p = 0.f;
        #pragma unroll
        for (int d = lane; d < DSUM; d += 64) p = fmaf(w[d], gs[d], p);
        #pragma unroll
        for (int off = 32; off; off >>= 1) p += __shfl_xor(p, off);
        if (lane == 0) {
            p += b1[jj];
            p = (p - rm1[jj]) * rsqrtf(rv1[jj] + EPSBN) * g1[jj] + be1[jj];
            h1[jj] = fmaxf(p, 0.f);
        }
    }
    __syncthreads();

    // layer 2: 64 outputs, dot length 128
    for (int r = 0; r < 16; ++r) {
        const int jj = wv * 16 + r;
        const float* w = W2 + (size_t)jj * 128;
        float p = fmaf(w[lane], h1[lane], 0.f) + w[lane + 64] * h1[lane + 64];
        #pragma unroll
        for (int off = 32; off; off >>= 1) p += __shfl_xor(p, off);
        if (lane == 0) {
            p += b2[jj];
            p = (p - rm2[jj]) * rsqrtf(rv2[jj] + EPSBN) * g2[jj] + be2[jj];
            h2[jj] = fmaxf(p, 0.f);
        }
    }
    __syncthreads();

    // layer 3: 64 outputs, dot length 64
    for (int r = 0; r < 16; ++r) {
        const int jj = wv * 16 + r;
        float p = W3[(size_t)jj * 64 + lane] * h2[lane];
        #pragma unroll
        for (int off = 32; off; off >>= 1) p += __shfl_xor(p, off);
        if (lane == 0) {
            p += b3[jj];
            coeff_out[b * PCADIM + jj] = p;
            coeff_ws[b * PCADIM + jj]  = p;
        }
    }
}

// ---------------- kernel 4: PCA inverse transform ----------------------------
__global__ __launch_bounds__(256) void k4_tpose(
    const float* __restrict__ coeff_ws,  // [NBATCH, PCADIM]
    const float* __restrict__ comp,      // [PCADIM, V3]
    const float* __restrict__ mean_,     // [V3]
    const float* __restrict__ scale_,    // [V3]
    float* __restrict__ tpose)           // [NBATCH, V3]
{
    __shared__ float sc[NBATCH * PCADIM];
    const int tid = threadIdx.x;
    for (int o = tid; o < NBATCH * PCADIM; o += 256) sc[o] = coeff_ws[o];
    __syncthreads();

    const int v = blockIdx.x * 256 + tid;
    if (v >= V3) return;

    float acc[NBATCH];
    #pragma unroll
    for (int s = 0; s < NBATCH; ++s) acc[s] = 0.f;

    for (int k = 0; k < PCADIM; ++k) {
        const float pv = comp[(size_t)k * V3 + v];
        #pragma unroll
        for (int s = 0; s < NBATCH; ++s)
            acc[s] = fmaf(sc[s * PCADIM + k], pv, acc[s]);
    }
    const float mn = mean_[v], scl = scale_[v];
    #pragma unroll
    for (int s = 0; s < NBATCH; ++s)
        tpose[(size_t)s * V3 + v] = (acc[s] + mn) * scl;
}

// ---------------- launcher ---------------------------------------------------
extern "C" void kernel_launch(void* const* d_in, const int* in_sizes, int n_in,
                              void* d_out, int out_size, void* d_ws, size_t ws_size,
                              hipStream_t stream) {
    const float* x      = (const float*)d_in[0];
    const float* logits = (const float*)d_in[1];
    const float* feat   = (const float*)d_in[2];
    const float* gsum   = (const float*)d_in[3];
    const float* W1  = (const float*)d_in[4];
    const float* b1  = (const float*)d_in[5];
    const float* g1  = (const float*)d_in[6];
    const float* be1 = (const float*)d_in[7];
    const float* rm1 = (const float*)d_in[8];
    const float* rv1 = (const float*)d_in[9];
    const float* W2  = (const float*)d_in[10];
    const float* b2  = (const float*)d_in[11];
    const float* g2  = (const float*)d_in[12];
    const float* be2 = (const float*)d_in[13];
    const float* rm2 = (const float*)d_in[14];
    const float* rv2 = (const float*)d_in[15];
    const float* W3  = (const float*)d_in[16];
    const float* b3  = (const float*)d_in[17];
    const float* comp  = (const float*)d_in[18];
    const float* mean_ = (const float*)d_in[19];
    const float* scale_= (const float*)d_in[20];
    const int* d_label = (const int*)d_in[21];

    float* out   = (float*)d_out;
    float* gv    = out + OFF_GV;
    float* gf    = out + OFF_GF;
    float* coeff = out + OFF_COEFF;
    float* tpose = out + OFF_TPOSE;

    unsigned long long* ws_mask = (unsigned long long*)d_ws;      // 64*108
    int*   ws_pos   = (int*)(ws_mask + BSAMP * NW);               // 64*6890
    int*   ws_count = ws_pos + BSAMP * NPTS;                      // 64
    float* coeff_ws = (float*)(ws_count + BSAMP);

    k0_mask  <<<BSAMP * 27,      256, 0, stream>>>(logits, d_label, ws_mask);
    k1_scan  <<<BSAMP,           256, 0, stream>>>(x, ws_mask, gv, ws_pos, ws_count);
    k2_gather<<<BSAMP * NCH,     256, 0, stream>>>(feat, ws_pos, gf);
    kz_zero  <<<BSAMP * NZBLK,   256, 0, stream>>>(ws_count, gf);
    k3_mlp   <<<NBATCH,          256, 0, stream>>>(gsum, W1, b1, g1, be1, rm1, rv1,
                                                   W2, b2, g2, be2, rm2, rv2, W3, b3,
                                                   coeff, coeff_ws);
    k4_tpose <<<(V3 + 255) / 256, 256, 0, stream>>>(coeff_ws, comp, mean_, scale_, tpose);
}

// Round 4
// 113.945 us; speedup vs baseline: 1.8500x; 1.2810x over previous
//
#include <hip/hip_runtime.h>

// ---------------- fixed problem geometry (validated by out_size) -------------
#define NBATCH   8
#define TT       8
#define NPTS     6890
#define KCLS     7
#define CCH      128
#define BSAMP    64            // NBATCH*TT
#define NOUT     1722          // n = NPTS/4
#define DSUM     512
#define PCADIM   64
#define V3       23106         // 7702*3
#define EPSBN    1e-5f

#define NW       108           // mask words per sample; 1 word == 1 chunk of 64 pts
#define PCH      64            // points per chunk
#define LDSP     129           // pad -> 2-way (free) on both LDS phases
#define CPG      4             // chunks per k2 block (pipelined)
#define NGRP     27            // 27 groups * 4 chunks = 108 chunks
#define RG       27            // kz rowgroups of 64 rows (27*64=1728 >= 1722)
#define K4B      91            // ceil(V3/256)

// output layout (flat f32)
#define OFF_GV     0
#define OFF_GF     (BSAMP * NOUT * 3)                 // 330624
#define OFF_COEFF  (OFF_GF + BSAMP * NOUT * CCH)      // 14437248
#define OFF_TPOSE  (OFF_COEFF + NBATCH * PCADIM)      // 14437760

// ---------------- kernel 0: per-point argmax -> selection bitmask ------------
__global__ __launch_bounds__(256) void k0_mask(
    const float* __restrict__ logits,    // [BSAMP, NPTS, KCLS]
    const int*   __restrict__ d_label,
    unsigned long long* __restrict__ ws_mask)  // [BSAMP, NW]
{
    const int b     = blockIdx.x / 27;
    const int chunk = blockIdx.x % 27;
    const int tid   = threadIdx.x;
    const int i     = chunk * 256 + tid;
    const int label = d_label[0];

    bool sel = false;
    if (i < NPTS) {
        const float* p = logits + ((size_t)b * NPTS + i) * KCLS;
        float best = p[0]; int bi = 0;
        #pragma unroll
        for (int k = 1; k < KCLS; ++k) {
            float v = p[k];
            if (v > best) { best = v; bi = k; }
        }
        sel = (bi == label);
    }
    const unsigned long long m = __ballot(sel);
    if ((tid & 63) == 0) {
        const int w = chunk * 4 + (tid >> 6);
        if (w < NW) ws_mask[b * NW + w] = m;
    }
}

// ------- kernel 1: fused {per-sample scan + gv gather} || {MLP} --------------
__global__ __launch_bounds__(256) void k_scan_mlp(
    const float* __restrict__ x,                 // [BSAMP, NPTS, 3]
    const unsigned long long* __restrict__ ws_mask,
    float* __restrict__ gv,                      // [BSAMP, NOUT, 3]
    int*   __restrict__ ws_spref,                // [BSAMP, NW]
    int*   __restrict__ ws_count,                // [BSAMP]
    const float* __restrict__ gsum,
    const float* __restrict__ W1, const float* __restrict__ b1,
    const float* __restrict__ g1, const float* __restrict__ be1,
    const float* __restrict__ rm1, const float* __restrict__ rv1,
    const float* __restrict__ W2, const float* __restrict__ b2,
    const float* __restrict__ g2, const float* __restrict__ be2,
    const float* __restrict__ rm2, const float* __restrict__ rv2,
    const float* __restrict__ W3, const float* __restrict__ b3,
    float* __restrict__ coeff_out, float* __restrict__ coeff_ws)
{
    const int tid = threadIdx.x;

    if (blockIdx.x < BSAMP) {
        // ---------------- scan part (blocks 0..63) ----------------
        const int b = blockIdx.x;
        __shared__ unsigned long long smask[NW];
        __shared__ int spref[NW + 1];

        if (tid < NW) smask[tid] = ws_mask[b * NW + tid];
        __syncthreads();
        if (tid == 0) {
            int run = 0;
            for (int w = 0; w < NW; ++w) { spref[w] = run; run += __popcll(smask[w]); }
            spref[NW] = run;
            ws_count[b] = run < NOUT ? run : NOUT;
        }
        __syncthreads();
        if (tid < NW) ws_spref[b * NW + tid] = spref[tid];

        const float* xb = x + (size_t)b * NPTS * 3;
        for (int i = tid; i < NPTS; i += 256) {
            const int w = i >> 6, lb6 = i & 63;
            const unsigned long long m = smask[w];
            if ((m >> lb6) & 1ull) {
                const int pos = spref[w] + __popcll(m & ((1ull << lb6) - 1ull));
                if (pos < NOUT) {
                    const size_t go = ((size_t)b * NOUT + pos) * 3;
                    gv[go + 0] = xb[(size_t)i * 3 + 0];
                    gv[go + 1] = xb[(size_t)i * 3 + 1];
                    gv[go + 2] = xb[(size_t)i * 3 + 2];
                }
            }
        }
    } else {
        // ---------------- MLP part (blocks 64..71) ----------------
        const int s    = blockIdx.x - BSAMP;
        const int lane = tid & 63;
        const int wv   = tid >> 6;

        __shared__ float gs[DSUM];
        __shared__ float h1[128];
        __shared__ float h2[64];

        for (int d = tid; d < DSUM; d += 256) {
            const float* p = gsum + ((size_t)s * TT) * DSUM + d;
            float m = p[0];
            #pragma unroll
            for (int t = 1; t < TT; ++t) m = fmaxf(m, p[(size_t)t * DSUM]);
            gs[d] = m;
        }
        __syncthreads();

        // layer 1: 128 outputs, dot length 512, 2-row ILP pairing
        for (int r = 0; r < 32; r += 2) {
            const int j0 = wv * 32 + r, j1 = j0 + 1;
            const float* w0 = W1 + (size_t)j0 * DSUM;
            const float* w1 = W1 + (size_t)j1 * DSUM;
            float pa = 0.f, pb = 0.f;
            #pragma unroll
            for (int d = lane; d < DSUM; d += 64) {
                const float gd = gs[d];
                pa = fmaf(w0[d], gd, pa);
                pb = fmaf(w1[d], gd, pb);
            }
            #pragma unroll
            for (int off = 32; off; off >>= 1) {
                pa += __shfl_xor(pa, off);
                pb += __shfl_xor(pb, off);
            }
            if (lane == 0) {
                pa += b1[j0];
                pa = (pa - rm1[j0]) * rsqrtf(rv1[j0] + EPSBN) * g1[j0] + be1[j0];
                h1[j0] = fmaxf(pa, 0.f);
                pb += b1[j1];
                pb = (pb - rm1[j1]) * rsqrtf(rv1[j1] + EPSBN) * g1[j1] + be1[j1];
                h1[j1] = fmaxf(pb, 0.f);
            }
        }
        __syncthreads();

        // layer 2: 64 outputs, dot length 128
        for (int r = 0; r < 16; ++r) {
            const int jj = wv * 16 + r;
            const float* w = W2 + (size_t)jj * 128;
            float p = w[lane] * h1[lane] + w[lane + 64] * h1[lane + 64];
            #pragma unroll
            for (int off = 32; off; off >>= 1) p += __shfl_xor(p, off);
            if (lane == 0) {
                p += b2[jj];
                p = (p - rm2[jj]) * rsqrtf(rv2[jj] + EPSBN) * g2[jj] + be2[jj];
                h2[jj] = fmaxf(p, 0.f);
            }
        }
        __syncthreads();

        // layer 3: 64 outputs, dot length 64
        for (int r = 0; r < 16; ++r) {
            const int jj = wv * 16 + r;
            float p = W3[(size_t)jj * 64 + lane] * h2[lane];
            #pragma unroll
            for (int off = 32; off; off >>= 1) p += __shfl_xor(p, off);
            if (lane == 0) {
                p += b3[jj];
                coeff_out[s * PCADIM + jj] = p;
                coeff_ws[s * PCADIM + jj]  = p;
            }
        }
    }
}

// ------- kernel 2: pipelined 4-chunk reg-staged coalesced gather -------------
__global__ __launch_bounds__(256, 4) void k2_gather(
    const float* __restrict__ feature,           // [BSAMP, CCH, NPTS]
    const unsigned long long* __restrict__ ws_mask,
    const int* __restrict__ ws_spref,
    float* __restrict__ gf)                      // [BSAMP, NOUT, CCH]
{
    __shared__ float lds[PCH * LDSP];            // 33 KB -> 4 blocks/CU
    __shared__ int   spos[PCH];
    __shared__ int   sel_list[PCH];
    __shared__ int   s_nsel;

    const int b   = blockIdx.x / NGRP;
    const int g   = blockIdx.x % NGRP;
    const int tid = threadIdx.x;
    const int pt2 = tid & 31;
    const int cg  = tid >> 5;
    const int p0  = pt2 * 2;
    const float* fbase = feature + (size_t)b * CCH * NPTS;

    float2 rc[16], rn[16];

    // prologue: load chunk g*CPG
    {
        const int i0 = g * (CPG * PCH);
        const int il = min(PCH, NPTS - i0);
        const float* fb = fbase + i0 + p0;
        if (p0 < il) {
            #pragma unroll
            for (int it = 0; it < 16; ++it)
                rc[it] = *(const float2*)(fb + (size_t)(cg + 8 * it) * NPTS);
        } else {
            #pragma unroll
            for (int it = 0; it < 16; ++it) rc[it] = make_float2(0.f, 0.f);
        }
    }

    #pragma unroll
    for (int c = 0; c < CPG; ++c) {
        const int chunk = g * CPG + c;

        // issue next chunk's loads early (overlap HBM latency with LDS+phaseB)
        if (c + 1 < CPG) {
            const int i1 = (chunk + 1) * PCH;
            const int il = min(PCH, NPTS - i1);
            const float* fb = fbase + i1 + p0;
            if (p0 < il) {
                #pragma unroll
                for (int it = 0; it < 16; ++it)
                    rn[it] = *(const float2*)(fb + (size_t)(cg + 8 * it) * NPTS);
            } else {
                #pragma unroll
                for (int it = 0; it < 16; ++it) rn[it] = make_float2(0.f, 0.f);
            }
        }

        __syncthreads();                          // LDS free (prev phase B done)

        // LDS transpose write (2-way banks, free)
        #pragma unroll
        for (int it = 0; it < 16; ++it) {
            const int cch = cg + 8 * it;
            lds[p0 * LDSP + cch]       = rc[it].x;
            lds[(p0 + 1) * LDSP + cch] = rc[it].y;
        }

        // selection from mask word + prefix (wave 0)
        if (tid < 64) {
            const unsigned long long m = ws_mask[b * NW + chunk];
            const int base = ws_spref[b * NW + chunk];
            const int sel  = (int)((m >> tid) & 1ull);
            const int pos  = base + __popcll(m & ((1ull << tid) - 1ull));
            const int sp   = (sel && pos < NOUT) ? pos : -1;
            spos[tid] = sp;
            const unsigned long long mm = __ballot(sp >= 0);
            const int before = __popcll(mm & ((1ull << tid) - 1ull));
            if (sp >= 0) sel_list[before] = tid;
            if (tid == 0) s_nsel = __popcll(mm);
        }
        __syncthreads();

        // phase B: coalesced 512B row writes for selected points
        const int nsel = s_nsel;
        const int cc = tid & 127;
        for (int s = tid >> 7; s < nsel; s += 2) {
            const int p = sel_list[s];
            gf[((size_t)b * NOUT + spos[p]) * CCH + cc] = lds[p * LDSP + cc];
        }

        if (c + 1 < CPG) {
            #pragma unroll
            for (int it = 0; it < 16; ++it) rc[it] = rn[it];
        }
    }
}

// ------- kernel 3: fused {gf/gv tail zero} || {PCA inverse transform} --------
__global__ __launch_bounds__(256) void kz4(
    const int*   __restrict__ ws_count,
    float*       __restrict__ gv,
    float*       __restrict__ gf,
    const float* __restrict__ coeff_ws,
    const float* __restrict__ comp,
    const float* __restrict__ mean_,
    const float* __restrict__ scale_,
    float*       __restrict__ tpose)
{
    const int blk = blockIdx.x;
    const int tid = threadIdx.x;

    if (blk < BSAMP * RG) {
        // tail-zero part: 64 rows per block
        const int b  = blk / RG;
        const int rg = blk % RG;
        const int j0 = rg * 64;
        const int cnt = ws_count[b];
        float4* gfb = (float4*)(gf + (size_t)b * NOUT * CCH);
        #pragma unroll
        for (int q = 0; q < 8; ++q) {
            const int f = tid + 256 * q;          // float4 index in 64-row group
            const int j = j0 + (f >> 5);
            if (j >= cnt && j < NOUT)
                gfb[(size_t)j * 32 + (f & 31)] = make_float4(0.f, 0.f, 0.f, 0.f);
        }
        if (tid < 64) {
            const int j = j0 + tid;
            if (j >= cnt && j < NOUT) {
                float* gp = gv + ((size_t)b * NOUT + j) * 3;
                gp[0] = 0.f; gp[1] = 0.f; gp[2] = 0.f;
            }
        }
    } else {
        // tpose part
        __shared__ float sc[NBATCH * PCADIM];
        for (int o = tid; o < NBATCH * PCADIM; o += 256) sc[o] = coeff_ws[o];
        __syncthreads();

        const int v = (blk - BSAMP * RG) * 256 + tid;
        if (v >= V3) return;

        float acc[NBATCH];
        #pragma unroll
        for (int s = 0; s < NBATCH; ++s) acc[s] = 0.f;
        for (int k = 0; k < PCADIM; ++k) {
            const float pv = comp[(size_t)k * V3 + v];
            #pragma unroll
            for (int s = 0; s < NBATCH; ++s)
                acc[s] = fmaf(sc[s * PCADIM + k], pv, acc[s]);
        }
        const float mn = mean_[v], scl = scale_[v];
        #pragma unroll
        for (int s = 0; s < NBATCH; ++s)
            tpose[(size_t)s * V3 + v] = (acc[s] + mn) * scl;
    }
}

// ---------------- launcher ---------------------------------------------------
extern "C" void kernel_launch(void* const* d_in, const int* in_sizes, int n_in,
                              void* d_out, int out_size, void* d_ws, size_t ws_size,
                              hipStream_t stream) {
    const float* x      = (const float*)d_in[0];
    const float* logits = (const float*)d_in[1];
    const float* feat   = (const float*)d_in[2];
    const float* gsum   = (const float*)d_in[3];
    const float* W1  = (const float*)d_in[4];
    const float* b1  = (const float*)d_in[5];
    const float* g1  = (const float*)d_in[6];
    const float* be1 = (const float*)d_in[7];
    const float* rm1 = (const float*)d_in[8];
    const float* rv1 = (const float*)d_in[9];
    const float* W2  = (const float*)d_in[10];
    const float* b2  = (const float*)d_in[11];
    const float* g2  = (const float*)d_in[12];
    const float* be2 = (const float*)d_in[13];
    const float* rm2 = (const float*)d_in[14];
    const float* rv2 = (const float*)d_in[15];
    const float* W3  = (const float*)d_in[16];
    const float* b3  = (const float*)d_in[17];
    const float* comp  = (const float*)d_in[18];
    const float* mean_ = (const float*)d_in[19];
    const float* scale_= (const float*)d_in[20];
    const int* d_label = (const int*)d_in[21];

    float* out   = (float*)d_out;
    float* gv    = out + OFF_GV;
    float* gf    = out + OFF_GF;
    float* coeff = out + OFF_COEFF;
    float* tpose = out + OFF_TPOSE;

    unsigned long long* ws_mask = (unsigned long long*)d_ws;      // 64*108 u64
    int*   ws_spref = (int*)(ws_mask + BSAMP * NW);               // 64*108 int
    int*   ws_count = ws_spref + BSAMP * NW;                      // 64
    float* coeff_ws = (float*)(ws_count + BSAMP);                 // 512

    k0_mask   <<<BSAMP * 27,        256, 0, stream>>>(logits, d_label, ws_mask);
    k_scan_mlp<<<BSAMP + NBATCH,    256, 0, stream>>>(x, ws_mask, gv, ws_spref, ws_count,
                                                      gsum, W1, b1, g1, be1, rm1, rv1,
                                                      W2, b2, g2, be2, rm2, rv2, W3, b3,
                                                      coeff, coeff_ws);
    k2_gather <<<BSAMP * NGRP,      256, 0, stream>>>(feat, ws_mask, ws_spref, gf);
    kz4       <<<BSAMP * RG + K4B,  256, 0, stream>>>(ws_count, gv, gf, coeff_ws,
                                                      comp, mean_, scale_, tpose);
}

// Round 5
// 100.717 us; speedup vs baseline: 2.0930x; 1.1313x over previous
//
#include <hip/hip_runtime.h>

// ---------------- fixed problem geometry (validated by out_size) -------------
#define NBATCH   8
#define TT       8
#define NPTS     6890
#define KCLS     7
#define CCH      128
#define BSAMP    64            // NBATCH*TT
#define NOUT     1722          // n = NPTS/4
#define DSUM     512
#define PCADIM   64
#define V3       23106         // 7702*3
#define EPSBN    1e-5f

#define NW       108           // mask words per sample; 1 word == 1 chunk of 64 pts
#define PCH      64            // points per chunk
#define LDSP     129           // pad -> 2-way (free) on both LDS phases
#define CPG      4             // chunks per k2 block (pipelined)
#define NGRP     27            // 27 groups * 4 chunks = 108 chunks
#define K4B      91            // ceil(V3/256) tpose blocks appended to k2 grid
#define NGATHER  (BSAMP * NGRP)

// output layout (flat f32)
#define OFF_GV     0
#define OFF_GF     (BSAMP * NOUT * 3)                 // 330624
#define OFF_COEFF  (OFF_GF + BSAMP * NOUT * CCH)      // 14437248
#define OFF_TPOSE  (OFF_COEFF + NBATCH * PCADIM)      // 14437760

// ---------------- kernel 0: per-point argmax -> selection bitmask ------------
__global__ __launch_bounds__(256) void k0_mask(
    const float* __restrict__ logits,    // [BSAMP, NPTS, KCLS]
    const int*   __restrict__ d_label,
    unsigned long long* __restrict__ ws_mask)  // [BSAMP, NW]
{
    const int b     = blockIdx.x / 27;
    const int chunk = blockIdx.x % 27;
    const int tid   = threadIdx.x;
    const int i     = chunk * 256 + tid;
    const int label = d_label[0];

    bool sel = false;
    if (i < NPTS) {
        const float* p = logits + ((size_t)b * NPTS + i) * KCLS;
        float best = p[0]; int bi = 0;
        #pragma unroll
        for (int k = 1; k < KCLS; ++k) {
            float v = p[k];
            if (v > best) { best = v; bi = k; }
        }
        sel = (bi == label);
    }
    const unsigned long long m = __ballot(sel);
    if ((tid & 63) == 0) {
        const int w = chunk * 4 + (tid >> 6);
        if (w < NW) ws_mask[b * NW + w] = m;
    }
}

// ------- kernel 1: fused {per-sample scan + gv gather + gv tail} || {MLP} ----
__global__ __launch_bounds__(256) void k_scan_mlp(
    const float* __restrict__ x,                 // [BSAMP, NPTS, 3]
    const unsigned long long* __restrict__ ws_mask,
    float* __restrict__ gv,                      // [BSAMP, NOUT, 3]
    int*   __restrict__ ws_spref,                // [BSAMP, NW]
    int*   __restrict__ ws_count,                // [BSAMP]
    const float* __restrict__ gsum,
    const float* __restrict__ W1, const float* __restrict__ b1,
    const float* __restrict__ g1, const float* __restrict__ be1,
    const float* __restrict__ rm1, const float* __restrict__ rv1,
    const float* __restrict__ W2, const float* __restrict__ b2,
    const float* __restrict__ g2, const float* __restrict__ be2,
    const float* __restrict__ rm2, const float* __restrict__ rv2,
    const float* __restrict__ W3, const float* __restrict__ b3,
    float* __restrict__ coeff_out, float* __restrict__ coeff_ws)
{
    const int tid = threadIdx.x;

    if (blockIdx.x < BSAMP) {
        // ---------------- scan part (blocks 0..63) ----------------
        const int b = blockIdx.x;
        __shared__ unsigned long long smask[NW];
        __shared__ int spref[NW + 1];

        if (tid < NW) smask[tid] = ws_mask[b * NW + tid];
        __syncthreads();
        if (tid == 0) {
            int run = 0;
            for (int w = 0; w < NW; ++w) { spref[w] = run; run += __popcll(smask[w]); }
            spref[NW] = run;
            ws_count[b] = run < NOUT ? run : NOUT;
        }
        __syncthreads();
        if (tid < NW) ws_spref[b * NW + tid] = spref[tid];

        const float* xb = x + (size_t)b * NPTS * 3;
        for (int i = tid; i < NPTS; i += 256) {
            const int w = i >> 6, lb6 = i & 63;
            const unsigned long long m = smask[w];
            if ((m >> lb6) & 1ull) {
                const int pos = spref[w] + __popcll(m & ((1ull << lb6) - 1ull));
                if (pos < NOUT) {
                    const size_t go = ((size_t)b * NOUT + pos) * 3;
                    gv[go + 0] = xb[(size_t)i * 3 + 0];
                    gv[go + 1] = xb[(size_t)i * 3 + 1];
                    gv[go + 2] = xb[(size_t)i * 3 + 2];
                }
            }
        }

        // gv tail zero (rows [cnt, NOUT))
        int cnt = spref[NW]; if (cnt > NOUT) cnt = NOUT;
        for (int j = cnt + tid; j < NOUT; j += 256) {
            float* gp = gv + ((size_t)b * NOUT + j) * 3;
            gp[0] = 0.f; gp[1] = 0.f; gp[2] = 0.f;
        }
    } else {
        // ---------------- MLP part (blocks 64..71) ----------------
        const int s    = blockIdx.x - BSAMP;
        const int lane = tid & 63;
        const int wv   = tid >> 6;

        __shared__ float gs[DSUM];
        __shared__ float h1[128];
        __shared__ float h2[64];

        for (int d = tid; d < DSUM; d += 256) {
            const float* p = gsum + ((size_t)s * TT) * DSUM + d;
            float m = p[0];
            #pragma unroll
            for (int t = 1; t < TT; ++t) m = fmaxf(m, p[(size_t)t * DSUM]);
            gs[d] = m;
        }
        __syncthreads();

        // layer 1: 128 outputs, dot length 512, 2-row ILP pairing
        for (int r = 0; r < 32; r += 2) {
            const int j0 = wv * 32 + r, j1 = j0 + 1;
            const float* w0 = W1 + (size_t)j0 * DSUM;
            const float* w1 = W1 + (size_t)j1 * DSUM;
            float pa = 0.f, pb = 0.f;
            #pragma unroll
            for (int d = lane; d < DSUM; d += 64) {
                const float gd = gs[d];
                pa = fmaf(w0[d], gd, pa);
                pb = fmaf(w1[d], gd, pb);
            }
            #pragma unroll
            for (int off = 32; off; off >>= 1) {
                pa += __shfl_xor(pa, off);
                pb += __shfl_xor(pb, off);
            }
            if (lane == 0) {
                pa += b1[j0];
                pa = (pa - rm1[j0]) * rsqrtf(rv1[j0] + EPSBN) * g1[j0] + be1[j0];
                h1[j0] = fmaxf(pa, 0.f);
                pb += b1[j1];
                pb = (pb - rm1[j1]) * rsqrtf(rv1[j1] + EPSBN) * g1[j1] + be1[j1];
                h1[j1] = fmaxf(pb, 0.f);
            }
        }
        __syncthreads();

        // layer 2: 64 outputs, dot length 128
        for (int r = 0; r < 16; ++r) {
            const int jj = wv * 16 + r;
            const float* w = W2 + (size_t)jj * 128;
            float p = w[lane] * h1[lane] + w[lane + 64] * h1[lane + 64];
            #pragma unroll
            for (int off = 32; off; off >>= 1) p += __shfl_xor(p, off);
            if (lane == 0) {
                p += b2[jj];
                p = (p - rm2[jj]) * rsqrtf(rv2[jj] + EPSBN) * g2[jj] + be2[jj];
                h2[jj] = fmaxf(p, 0.f);
            }
        }
        __syncthreads();

        // layer 3: 64 outputs, dot length 64
        for (int r = 0; r < 16; ++r) {
            const int jj = wv * 16 + r;
            float p = W3[(size_t)jj * 64 + lane] * h2[lane];
            #pragma unroll
            for (int off = 32; off; off >>= 1) p += __shfl_xor(p, off);
            if (lane == 0) {
                p += b3[jj];
                coeff_out[s * PCADIM + jj] = p;
                coeff_ws[s * PCADIM + jj]  = p;
            }
        }
    }
}

// ------- kernel 2: pipelined gather + gf tail-zero share || tpose ------------
__global__ __launch_bounds__(256, 4) void k2_fused(
    const float* __restrict__ feature,           // [BSAMP, CCH, NPTS]
    const unsigned long long* __restrict__ ws_mask,
    const int* __restrict__ ws_spref,
    const int* __restrict__ ws_count,
    float* __restrict__ gf,                      // [BSAMP, NOUT, CCH]
    const float* __restrict__ coeff_ws,
    const float* __restrict__ comp,
    const float* __restrict__ mean_,
    const float* __restrict__ scale_,
    float* __restrict__ tpose)
{
    __shared__ float lds[PCH * LDSP];            // 33 KB -> 4 blocks/CU
    __shared__ int   spos[PCH];
    __shared__ int   sel_list[PCH];
    __shared__ int   s_nsel;

    const int tid = threadIdx.x;

    if (blockIdx.x >= NGATHER) {
        // ---------------- tpose part (91 blocks) ----------------
        float* sc = lds;                          // reuse LDS for coeff
        for (int o = tid; o < NBATCH * PCADIM; o += 256) sc[o] = coeff_ws[o];
        __syncthreads();

        const int v = (blockIdx.x - NGATHER) * 256 + tid;
        if (v >= V3) return;

        float acc[NBATCH];
        #pragma unroll
        for (int s = 0; s < NBATCH; ++s) acc[s] = 0.f;
        for (int k = 0; k < PCADIM; ++k) {
            const float pv = comp[(size_t)k * V3 + v];
            #pragma unroll
            for (int s = 0; s < NBATCH; ++s)
                acc[s] = fmaf(sc[s * PCADIM + k], pv, acc[s]);
        }
        const float mn = mean_[v], scl = scale_[v];
        #pragma unroll
        for (int s = 0; s < NBATCH; ++s)
            tpose[(size_t)s * V3 + v] = (acc[s] + mn) * scl;
        return;
    }

    // ---------------- gather part ----------------
    const int b   = blockIdx.x / NGRP;
    const int g   = blockIdx.x % NGRP;
    const int pt2 = tid & 31;
    const int cg  = tid >> 5;
    const int p0  = pt2 * 2;
    const float* fbase = feature + (size_t)b * CCH * NPTS;

    float2 rc[16], rn[16];

    // prologue: load chunk g*CPG
    {
        const int i0 = g * (CPG * PCH);
        const int il = min(PCH, NPTS - i0);
        const float* fb = fbase + i0 + p0;
        if (p0 < il) {
            #pragma unroll
            for (int it = 0; it < 16; ++it)
                rc[it] = *(const float2*)(fb + (size_t)(cg + 8 * it) * NPTS);
        } else {
            #pragma unroll
            for (int it = 0; it < 16; ++it) rc[it] = make_float2(0.f, 0.f);
        }
    }

    #pragma unroll
    for (int c = 0; c < CPG; ++c) {
        const int chunk = g * CPG + c;

        // issue next chunk's loads early (overlap HBM latency with LDS+phaseB)
        if (c + 1 < CPG) {
            const int i1 = (chunk + 1) * PCH;
            const int il = min(PCH, NPTS - i1);
            const float* fb = fbase + i1 + p0;
            if (p0 < il) {
                #pragma unroll
                for (int it = 0; it < 16; ++it)
                    rn[it] = *(const float2*)(fb + (size_t)(cg + 8 * it) * NPTS);
            } else {
                #pragma unroll
                for (int it = 0; it < 16; ++it) rn[it] = make_float2(0.f, 0.f);
            }
        }

        __syncthreads();                          // LDS free (prev phase B done)

        // LDS transpose write (2-way banks, free)
        #pragma unroll
        for (int it = 0; it < 16; ++it) {
            const int cch = cg + 8 * it;
            lds[p0 * LDSP + cch]       = rc[it].x;
            lds[(p0 + 1) * LDSP + cch] = rc[it].y;
        }

        // selection from mask word + prefix (wave 0)
        if (tid < 64) {
            const unsigned long long m = ws_mask[b * NW + chunk];
            const int base = ws_spref[b * NW + chunk];
            const int sel  = (int)((m >> tid) & 1ull);
            const int pos  = base + __popcll(m & ((1ull << tid) - 1ull));
            const int sp   = (sel && pos < NOUT) ? pos : -1;
            spos[tid] = sp;
            const unsigned long long mm = __ballot(sp >= 0);
            const int before = __popcll(mm & ((1ull << tid) - 1ull));
            if (sp >= 0) sel_list[before] = tid;
            if (tid == 0) s_nsel = __popcll(mm);
        }
        __syncthreads();

        // phase B: coalesced 512B row writes for selected points
        const int nsel = s_nsel;
        const int cc = tid & 127;
        for (int s = tid >> 7; s < nsel; s += 2) {
            const int p = sel_list[s];
            gf[((size_t)b * NOUT + spos[p]) * CCH + cc] = lds[p * LDSP + cc];
        }

        if (c + 1 < CPG) {
            #pragma unroll
            for (int it = 0; it < 16; ++it) rc[it] = rn[it];
        }
    }

    // gf tail-zero: this block zeroes its 1/NGRP share of rows [cnt, NOUT)
    {
        const int cnt   = ws_count[b];
        const int tail  = NOUT - cnt;
        if (tail > 0) {
            const int share = (tail + NGRP - 1) / NGRP;
            const int r0    = cnt + g * share;
            const int r1    = min(r0 + share, NOUT);
            const int nrows = r1 - r0;
            if (nrows > 0) {
                float4* base4 = (float4*)(gf + ((size_t)b * NOUT + r0) * CCH);
                const int total = nrows * 32;     // float4 per row = 32
                for (int f = tid; f < total; f += 256)
                    base4[f] = make_float4(0.f, 0.f, 0.f, 0.f);
            }
        }
    }
}

// ---------------- launcher ---------------------------------------------------
extern "C" void kernel_launch(void* const* d_in, const int* in_sizes, int n_in,
                              void* d_out, int out_size, void* d_ws, size_t ws_size,
                              hipStream_t stream) {
    const float* x      = (const float*)d_in[0];
    const float* logits = (const float*)d_in[1];
    const float* feat   = (const float*)d_in[2];
    const float* gsum   = (const float*)d_in[3];
    const float* W1  = (const float*)d_in[4];
    const float* b1  = (const float*)d_in[5];
    const float* g1  = (const float*)d_in[6];
    const float* be1 = (const float*)d_in[7];
    const float* rm1 = (const float*)d_in[8];
    const float* rv1 = (const float*)d_in[9];
    const float* W2  = (const float*)d_in[10];
    const float* b2  = (const float*)d_in[11];
    const float* g2  = (const float*)d_in[12];
    const float* be2 = (const float*)d_in[13];
    const float* rm2 = (const float*)d_in[14];
    const float* rv2 = (const float*)d_in[15];
    const float* W3  = (const float*)d_in[16];
    const float* b3  = (const float*)d_in[17];
    const float* comp  = (const float*)d_in[18];
    const float* mean_ = (const float*)d_in[19];
    const float* scale_= (const float*)d_in[20];
    const int* d_label = (const int*)d_in[21];

    float* out   = (float*)d_out;
    float* gv    = out + OFF_GV;
    float* gf    = out + OFF_GF;
    float* coeff = out + OFF_COEFF;
    float* tpose = out + OFF_TPOSE;

    unsigned long long* ws_mask = (unsigned long long*)d_ws;      // 64*108 u64
    int*   ws_spref = (int*)(ws_mask + BSAMP * NW);               // 64*108 int
    int*   ws_count = ws_spref + BSAMP * NW;                      // 64
    float* coeff_ws = (float*)(ws_count + BSAMP);                 // 512

    k0_mask   <<<BSAMP * 27,       256, 0, stream>>>(logits, d_label, ws_mask);
    k_scan_mlp<<<BSAMP + NBATCH,   256, 0, stream>>>(x, ws_mask, gv, ws_spref, ws_count,
                                                     gsum, W1, b1, g1, be1, rm1, rv1,
                                                     W2, b2, g2, be2, rm2, rv2, W3, b3,
                                                     coeff, coeff_ws);
    k2_fused  <<<NGATHER + K4B,    256, 0, stream>>>(feat, ws_mask, ws_spref, ws_count,
                                                     gf, coeff_ws, comp, mean_, scale_,
                                                     tpose);
}

// Round 6
// 99.068 us; speedup vs baseline: 2.1278x; 1.0166x over previous
//
#include <hip/hip_runtime.h>

// ---------------- fixed problem geometry (validated by out_size) -------------
#define NBATCH   8
#define TT       8
#define NPTS     6890
#define KCLS     7
#define CCH      128
#define BSAMP    64            // NBATCH*TT
#define NOUT     1722          // n = NPTS/4
#define DSUM     512
#define PCADIM   64
#define V3       23106         // 7702*3
#define EPSBN    1e-5f

#define NW       108           // mask words per sample; 1 word == 1 chunk of 64 pts
#define PCH      64            // points per chunk
#define LDSP     129           // pad -> 2-way (free) on both LDS phases
#define CPG      6             // chunks per gather block (pipelined)
#define NGRP     18            // 18 groups * 6 chunks = 108 chunks
#define K4B      91            // ceil(V3/256) tpose blocks (placed FIRST in grid)
#define NGATHER  (BSAMP * NGRP)

// output layout (flat f32)
#define OFF_GV     0
#define OFF_GF     (BSAMP * NOUT * 3)                 // 330624
#define OFF_COEFF  (OFF_GF + BSAMP * NOUT * CCH)      // 14437248
#define OFF_TPOSE  (OFF_COEFF + NBATCH * PCADIM)      // 14437760

// ------- kernel 1: {per-sample argmax+scan+gv (64 blocks)} || {MLP (8)} ------
__global__ __launch_bounds__(256) void k_prep(
    const float* __restrict__ logits,            // [BSAMP, NPTS, KCLS]
    const int*   __restrict__ d_label,
    const float* __restrict__ x,                 // [BSAMP, NPTS, 3]
    unsigned long long* __restrict__ ws_mask,    // [BSAMP, NW]
    float* __restrict__ gv,                      // [BSAMP, NOUT, 3]
    int*   __restrict__ ws_spref,                // [BSAMP, NW]
    int*   __restrict__ ws_count,                // [BSAMP]
    const float* __restrict__ gsum,
    const float* __restrict__ W1, const float* __restrict__ b1,
    const float* __restrict__ g1, const float* __restrict__ be1,
    const float* __restrict__ rm1, const float* __restrict__ rv1,
    const float* __restrict__ W2, const float* __restrict__ b2,
    const float* __restrict__ g2, const float* __restrict__ be2,
    const float* __restrict__ rm2, const float* __restrict__ rv2,
    const float* __restrict__ W3, const float* __restrict__ b3,
    float* __restrict__ coeff_out, float* __restrict__ coeff_ws)
{
    const int tid = threadIdx.x;

    if (blockIdx.x < BSAMP) {
        // ------------- mask + scan + gv part (blocks 0..63) -------------
        const int b = blockIdx.x;
        const int label = d_label[0];
        __shared__ unsigned long long smask[NW];
        __shared__ int spref[NW + 1];

        const float* lb = logits + (size_t)b * NPTS * KCLS;
        #pragma unroll 1
        for (int r = 0; r < 27; ++r) {
            const int i = r * 256 + tid;
            bool sel = false;
            if (i < NPTS) {
                const float* p = lb + (size_t)i * KCLS;
                float best = p[0]; int bi = 0;
                #pragma unroll
                for (int k = 1; k < KCLS; ++k) {
                    float v = p[k];
                    if (v > best) { best = v; bi = k; }
                }
                sel = (bi == label);
            }
            const unsigned long long m = __ballot(sel);
            if ((tid & 63) == 0) {
                const int w = r * 4 + (tid >> 6);
                if (w < NW) smask[w] = m;
            }
        }
        __syncthreads();

        if (tid == 0) {
            int run = 0;
            for (int w = 0; w < NW; ++w) { spref[w] = run; run += __popcll(smask[w]); }
            spref[NW] = run;
            ws_count[b] = run < NOUT ? run : NOUT;
        }
        __syncthreads();
        if (tid < NW) {
            ws_mask [b * NW + tid] = smask[tid];
            ws_spref[b * NW + tid] = spref[tid];
        }

        const float* xb = x + (size_t)b * NPTS * 3;
        for (int i = tid; i < NPTS; i += 256) {
            const int w = i >> 6, lb6 = i & 63;
            const unsigned long long m = smask[w];
            if ((m >> lb6) & 1ull) {
                const int pos = spref[w] + __popcll(m & ((1ull << lb6) - 1ull));
                if (pos < NOUT) {
                    const size_t go = ((size_t)b * NOUT + pos) * 3;
                    gv[go + 0] = xb[(size_t)i * 3 + 0];
                    gv[go + 1] = xb[(size_t)i * 3 + 1];
                    gv[go + 2] = xb[(size_t)i * 3 + 2];
                }
            }
        }

        // gv tail zero (rows [cnt, NOUT))
        int cnt = spref[NW]; if (cnt > NOUT) cnt = NOUT;
        for (int j = cnt + tid; j < NOUT; j += 256) {
            float* gp = gv + ((size_t)b * NOUT + j) * 3;
            gp[0] = 0.f; gp[1] = 0.f; gp[2] = 0.f;
        }
    } else {
        // ------------- MLP part (blocks 64..71) -------------
        const int s    = blockIdx.x - BSAMP;
        const int lane = tid & 63;
        const int wv   = tid >> 6;

        __shared__ float gs[DSUM];
        __shared__ float h1[128];
        __shared__ float h2[64];

        for (int d = tid; d < DSUM; d += 256) {
            const float* p = gsum + ((size_t)s * TT) * DSUM + d;
            float m = p[0];
            #pragma unroll
            for (int t = 1; t < TT; ++t) m = fmaxf(m, p[(size_t)t * DSUM]);
            gs[d] = m;
        }
        __syncthreads();

        // layer 1: 128 outputs, dot length 512, 2-row ILP pairing
        for (int r = 0; r < 32; r += 2) {
            const int j0 = wv * 32 + r, j1 = j0 + 1;
            const float* w0 = W1 + (size_t)j0 * DSUM;
            const float* w1 = W1 + (size_t)j1 * DSUM;
            float pa = 0.f, pb = 0.f;
            #pragma unroll
            for (int d = lane; d < DSUM; d += 64) {
                const float gd = gs[d];
                pa = fmaf(w0[d], gd, pa);
                pb = fmaf(w1[d], gd, pb);
            }
            #pragma unroll
            for (int off = 32; off; off >>= 1) {
                pa += __shfl_xor(pa, off);
                pb += __shfl_xor(pb, off);
            }
            if (lane == 0) {
                pa += b1[j0];
                pa = (pa - rm1[j0]) * rsqrtf(rv1[j0] + EPSBN) * g1[j0] + be1[j0];
                h1[j0] = fmaxf(pa, 0.f);
                pb += b1[j1];
                pb = (pb - rm1[j1]) * rsqrtf(rv1[j1] + EPSBN) * g1[j1] + be1[j1];
                h1[j1] = fmaxf(pb, 0.f);
            }
        }
        __syncthreads();

        // layer 2: 64 outputs, dot length 128
        for (int r = 0; r < 16; ++r) {
            const int jj = wv * 16 + r;
            const float* w = W2 + (size_t)jj * 128;
            float p = w[lane] * h1[lane] + w[lane + 64] * h1[lane + 64];
            #pragma unroll
            for (int off = 32; off; off >>= 1) p += __shfl_xor(p, off);
            if (lane == 0) {
                p += b2[jj];
                p = (p - rm2[jj]) * rsqrtf(rv2[jj] + EPSBN) * g2[jj] + be2[jj];
                h2[jj] = fmaxf(p, 0.f);
            }
        }
        __syncthreads();

        // layer 3: 64 outputs, dot length 64
        for (int r = 0; r < 16; ++r) {
            const int jj = wv * 16 + r;
            float p = W3[(size_t)jj * 64 + lane] * h2[lane];
            #pragma unroll
            for (int off = 32; off; off >>= 1) p += __shfl_xor(p, off);
            if (lane == 0) {
                p += b3[jj];
                coeff_out[s * PCADIM + jj] = p;
                coeff_ws[s * PCADIM + jj]  = p;
            }
        }
    }
}

// ------- kernel 2: {tpose (first 91 blocks)} || {pipelined gather} -----------
__global__ __launch_bounds__(256, 4) void k_gather(
    const float* __restrict__ feature,           // [BSAMP, CCH, NPTS]
    const unsigned long long* __restrict__ ws_mask,
    const int* __restrict__ ws_spref,
    const int* __restrict__ ws_count,
    float* __restrict__ gf,                      // [BSAMP, NOUT, CCH]
    const float* __restrict__ coeff_ws,
    const float* __restrict__ comp,
    const float* __restrict__ mean_,
    const float* __restrict__ scale_,
    float* __restrict__ tpose)
{
    __shared__ float lds[PCH * LDSP];            // 33 KB -> 4 blocks/CU
    __shared__ int   spos[PCH];
    __shared__ int   sel_list[PCH];
    __shared__ int   s_nsel;

    const int tid = threadIdx.x;

    if (blockIdx.x < K4B) {
        // ---------------- tpose part (blocks 0..90, launched first) --------
        float* sc = lds;                          // reuse LDS for coeff
        for (int o = tid; o < NBATCH * PCADIM; o += 256) sc[o] = coeff_ws[o];
        __syncthreads();

        const int v = blockIdx.x * 256 + tid;
        if (v >= V3) return;

        float acc[NBATCH];
        #pragma unroll
        for (int s = 0; s < NBATCH; ++s) acc[s] = 0.f;
        for (int k = 0; k < PCADIM; ++k) {
            const float pv = comp[(size_t)k * V3 + v];
            #pragma unroll
            for (int s = 0; s < NBATCH; ++s)
                acc[s] = fmaf(sc[s * PCADIM + k], pv, acc[s]);
        }
        const float mn = mean_[v], scl = scale_[v];
        #pragma unroll
        for (int s = 0; s < NBATCH; ++s)
            tpose[(size_t)s * V3 + v] = (acc[s] + mn) * scl;
        return;
    }

    // ---------------- gather part ----------------
    const int gb  = blockIdx.x - K4B;
    const int b   = gb / NGRP;
    const int g   = gb % NGRP;
    const int pt2 = tid & 31;
    const int cg  = tid >> 5;
    const int p0  = pt2 * 2;
    const float* fbase = feature + (size_t)b * CCH * NPTS;

    float2 rc[16], rn[16];

    // prologue: issue loads for chunk g*CPG
    {
        const int i0 = g * (CPG * PCH);
        const int il = min(PCH, NPTS - i0);
        const float* fb = fbase + i0 + p0;
        if (p0 < il) {
            #pragma unroll
            for (int it = 0; it < 16; ++it)
                rc[it] = *(const float2*)(fb + (size_t)(cg + 8 * it) * NPTS);
        } else {
            #pragma unroll
            for (int it = 0; it < 16; ++it) rc[it] = make_float2(0.f, 0.f);
        }
    }

    // gf tail-zero share issued EARLY (independent stores hide under load wait)
    {
        const int cnt  = ws_count[b];
        const int tail = NOUT - cnt;
        if (tail > 0) {
            const int share = (tail + NGRP - 1) / NGRP;
            const int r0    = cnt + g * share;
            const int r1    = min(r0 + share, NOUT);
            const int nrows = r1 - r0;
            if (nrows > 0) {
                float4* base4 = (float4*)(gf + ((size_t)b * NOUT + r0) * CCH);
                const int total = nrows * 32;     // float4 per row = 32
                for (int f = tid; f < total; f += 256)
                    base4[f] = make_float4(0.f, 0.f, 0.f, 0.f);
            }
        }
    }

    #pragma unroll
    for (int c = 0; c < CPG; ++c) {
        const int chunk = g * CPG + c;

        // issue next chunk's loads early (overlap HBM latency with LDS+phaseB)
        if (c + 1 < CPG) {
            const int i1 = (chunk + 1) * PCH;
            const int il = min(PCH, NPTS - i1);
            const float* fb = fbase + i1 + p0;
            if (p0 < il) {
                #pragma unroll
                for (int it = 0; it < 16; ++it)
                    rn[it] = *(const float2*)(fb + (size_t)(cg + 8 * it) * NPTS);
            } else {
                #pragma unroll
                for (int it = 0; it < 16; ++it) rn[it] = make_float2(0.f, 0.f);
            }
        }

        __syncthreads();                          // LDS free (prev phase B done)

        // LDS transpose write (2-way banks, free)
        #pragma unroll
        for (int it = 0; it < 16; ++it) {
            const int cch = cg + 8 * it;
            lds[p0 * LDSP + cch]       = rc[it].x;
            lds[(p0 + 1) * LDSP + cch] = rc[it].y;
        }

        // selection from mask word + prefix (wave 0)
        if (tid < 64) {
            const unsigned long long m = ws_mask[b * NW + chunk];
            const int base = ws_spref[b * NW + chunk];
            const int sel  = (int)((m >> tid) & 1ull);
            const int pos  = base + __popcll(m & ((1ull << tid) - 1ull));
            const int sp   = (sel && pos < NOUT) ? pos : -1;
            spos[tid] = sp;
            const unsigned long long mm = __ballot(sp >= 0);
            const int before = __popcll(mm & ((1ull << tid) - 1ull));
            if (sp >= 0) sel_list[before] = tid;
            if (tid == 0) s_nsel = __popcll(mm);
        }
        __syncthreads();

        // phase B: coalesced 512B row writes for selected points
        const int nsel = s_nsel;
        const int cc = tid & 127;
        for (int s = tid >> 7; s < nsel; s += 2) {
            const int p = sel_list[s];
            gf[((size_t)b * NOUT + spos[p]) * CCH + cc] = lds[p * LDSP + cc];
        }

        if (c + 1 < CPG) {
            #pragma unroll
            for (int it = 0; it < 16; ++it) rc[it] = rn[it];
        }
    }
}

// ---------------- launcher ---------------------------------------------------
extern "C" void kernel_launch(void* const* d_in, const int* in_sizes, int n_in,
                              void* d_out, int out_size, void* d_ws, size_t ws_size,
                              hipStream_t stream) {
    const float* x      = (const float*)d_in[0];
    const float* logits = (const float*)d_in[1];
    const float* feat   = (const float*)d_in[2];
    const float* gsum   = (const float*)d_in[3];
    const float* W1  = (const float*)d_in[4];
    const float* b1  = (const float*)d_in[5];
    const float* g1  = (const float*)d_in[6];
    const float* be1 = (const float*)d_in[7];
    const float* rm1 = (const float*)d_in[8];
    const float* rv1 = (const float*)d_in[9];
    const float* W2  = (const float*)d_in[10];
    const float* b2  = (const float*)d_in[11];
    const float* g2  = (const float*)d_in[12];
    const float* be2 = (const float*)d_in[13];
    const float* rm2 = (const float*)d_in[14];
    const float* rv2 = (const float*)d_in[15];
    const float* W3  = (const float*)d_in[16];
    const float* b3  = (const float*)d_in[17];
    const float* comp  = (const float*)d_in[18];
    const float* mean_ = (const float*)d_in[19];
    const float* scale_= (const float*)d_in[20];
    const int* d_label = (const int*)d_in[21];

    float* out   = (float*)d_out;
    float* gv    = out + OFF_GV;
    float* gf    = out + OFF_GF;
    float* coeff = out + OFF_COEFF;
    float* tpose = out + OFF_TPOSE;

    unsigned long long* ws_mask = (unsigned long long*)d_ws;      // 64*108 u64
    int*   ws_spref = (int*)(ws_mask + BSAMP * NW);               // 64*108 int
    int*   ws_count = ws_spref + BSAMP * NW;                      // 64
    float* coeff_ws = (float*)(ws_count + BSAMP);                 // 512

    k_prep  <<<BSAMP + NBATCH,  256, 0, stream>>>(logits, d_label, x, ws_mask, gv,
                                                  ws_spref, ws_count,
                                                  gsum, W1, b1, g1, be1, rm1, rv1,
                                                  W2, b2, g2, be2, rm2, rv2, W3, b3,
                                                  coeff, coeff_ws);
    k_gather<<<K4B + NGATHER,   256, 0, stream>>>(feat, ws_mask, ws_spref, ws_count,
                                                  gf, coeff_ws, comp, mean_, scale_,
                                                  tpose);
}

// Round 7
// 92.034 us; speedup vs baseline: 2.2905x; 1.0764x over previous
//
#include <hip/hip_runtime.h>

// ---------------- fixed problem geometry (validated by out_size) -------------
#define NBATCH   8
#define TT       8
#define NPTS     6890
#define KCLS     7
#define CCH      128
#define BSAMP    64            // NBATCH*TT
#define NOUT     1722          // n = NPTS/4
#define DSUM     512
#define PCADIM   64
#define V3       23106         // 7702*3
#define EPSBN    1e-5f

#define NW       108           // mask words per sample (64 pts each)
#define PCH      128           // points per gather chunk (= 2 mask words)
#define NCHK     54            // ceil(NPTS/PCH); last chunk = 106 pts (even)
#define CHB      2             // channel blocks (64 ch each)
#define CHN      64            // channels per ch-block
#define LDSQ     129           // padded point dim (channel-major LDS)
#define CPG      6             // chunks per gather block (pipelined)
#define NGRP     9             // 9 groups * 6 chunks = 54 chunks
#define K4B      91            // ceil(V3/256) tpose blocks (first in grid)
#define NGATHER  (BSAMP * CHB * NGRP)   // 1152

// output layout (flat f32)
#define OFF_GV     0
#define OFF_GF     (BSAMP * NOUT * 3)                 // 330624
#define OFF_COEFF  (OFF_GF + BSAMP * NOUT * CCH)      // 14437248
#define OFF_TPOSE  (OFF_COEFF + NBATCH * PCADIM)      // 14437760

// ------- kernel 1: {per-sample argmax+scan+gv (64 blocks)} || {MLP (8)} ------
__global__ __launch_bounds__(256) void k_prep(
    const float* __restrict__ logits,            // [BSAMP, NPTS, KCLS]
    const int*   __restrict__ d_label,
    const float* __restrict__ x,                 // [BSAMP, NPTS, 3]
    unsigned long long* __restrict__ ws_mask,    // [BSAMP, NW]
    float* __restrict__ gv,                      // [BSAMP, NOUT, 3]
    int*   __restrict__ ws_spref,                // [BSAMP, NW]
    int*   __restrict__ ws_count,                // [BSAMP]
    const float* __restrict__ gsum,
    const float* __restrict__ W1, const float* __restrict__ b1,
    const float* __restrict__ g1, const float* __restrict__ be1,
    const float* __restrict__ rm1, const float* __restrict__ rv1,
    const float* __restrict__ W2, const float* __restrict__ b2,
    const float* __restrict__ g2, const float* __restrict__ be2,
    const float* __restrict__ rm2, const float* __restrict__ rv2,
    const float* __restrict__ W3, const float* __restrict__ b3,
    float* __restrict__ coeff_out, float* __restrict__ coeff_ws)
{
    const int tid = threadIdx.x;

    if (blockIdx.x < BSAMP) {
        // ------------- mask + scan + gv part (blocks 0..63) -------------
        const int b = blockIdx.x;
        const int label = d_label[0];
        __shared__ unsigned long long smask[NW];
        __shared__ int spref[NW + 1];

        const float* lb = logits + (size_t)b * NPTS * KCLS;
        #pragma unroll 1
        for (int r = 0; r < 27; ++r) {
            const int i = r * 256 + tid;
            bool sel = false;
            if (i < NPTS) {
                const float* p = lb + (size_t)i * KCLS;
                float best = p[0]; int bi = 0;
                #pragma unroll
                for (int k = 1; k < KCLS; ++k) {
                    float v = p[k];
                    if (v > best) { best = v; bi = k; }
                }
                sel = (bi == label);
            }
            const unsigned long long m = __ballot(sel);
            if ((tid & 63) == 0) {
                const int w = r * 4 + (tid >> 6);
                if (w < NW) smask[w] = m;
            }
        }
        __syncthreads();

        if (tid == 0) {
            int run = 0;
            for (int w = 0; w < NW; ++w) { spref[w] = run; run += __popcll(smask[w]); }
            spref[NW] = run;
            ws_count[b] = run < NOUT ? run : NOUT;
        }
        __syncthreads();
        if (tid < NW) {
            ws_mask [b * NW + tid] = smask[tid];
            ws_spref[b * NW + tid] = spref[tid];
        }

        const float* xb = x + (size_t)b * NPTS * 3;
        for (int i = tid; i < NPTS; i += 256) {
            const int w = i >> 6, lb6 = i & 63;
            const unsigned long long m = smask[w];
            if ((m >> lb6) & 1ull) {
                const int pos = spref[w] + __popcll(m & ((1ull << lb6) - 1ull));
                if (pos < NOUT) {
                    const size_t go = ((size_t)b * NOUT + pos) * 3;
                    gv[go + 0] = xb[(size_t)i * 3 + 0];
                    gv[go + 1] = xb[(size_t)i * 3 + 1];
                    gv[go + 2] = xb[(size_t)i * 3 + 2];
                }
            }
        }

        // gv tail zero (rows [cnt, NOUT))
        int cnt = spref[NW]; if (cnt > NOUT) cnt = NOUT;
        for (int j = cnt + tid; j < NOUT; j += 256) {
            float* gp = gv + ((size_t)b * NOUT + j) * 3;
            gp[0] = 0.f; gp[1] = 0.f; gp[2] = 0.f;
        }
    } else {
        // ------------- MLP part (blocks 64..71) -------------
        const int s    = blockIdx.x - BSAMP;
        const int lane = tid & 63;
        const int wv   = tid >> 6;

        __shared__ float gs[DSUM];
        __shared__ float h1[128];
        __shared__ float h2[64];

        for (int d = tid; d < DSUM; d += 256) {
            const float* p = gsum + ((size_t)s * TT) * DSUM + d;
            float m = p[0];
            #pragma unroll
            for (int t = 1; t < TT; ++t) m = fmaxf(m, p[(size_t)t * DSUM]);
            gs[d] = m;
        }
        __syncthreads();

        for (int r = 0; r < 32; r += 2) {
            const int j0 = wv * 32 + r, j1 = j0 + 1;
            const float* w0 = W1 + (size_t)j0 * DSUM;
            const float* w1 = W1 + (size_t)j1 * DSUM;
            float pa = 0.f, pb = 0.f;
            #pragma unroll
            for (int d = lane; d < DSUM; d += 64) {
                const float gd = gs[d];
                pa = fmaf(w0[d], gd, pa);
                pb = fmaf(w1[d], gd, pb);
            }
            #pragma unroll
            for (int off = 32; off; off >>= 1) {
                pa += __shfl_xor(pa, off);
                pb += __shfl_xor(pb, off);
            }
            if (lane == 0) {
                pa += b1[j0];
                pa = (pa - rm1[j0]) * rsqrtf(rv1[j0] + EPSBN) * g1[j0] + be1[j0];
                h1[j0] = fmaxf(pa, 0.f);
                pb += b1[j1];
                pb = (pb - rm1[j1]) * rsqrtf(rv1[j1] + EPSBN) * g1[j1] + be1[j1];
                h1[j1] = fmaxf(pb, 0.f);
            }
        }
        __syncthreads();

        for (int r = 0; r < 16; ++r) {
            const int jj = wv * 16 + r;
            const float* w = W2 + (size_t)jj * 128;
            float p = w[lane] * h1[lane] + w[lane + 64] * h1[lane + 64];
            #pragma unroll
            for (int off = 32; off; off >>= 1) p += __shfl_xor(p, off);
            if (lane == 0) {
                p += b2[jj];
                p = (p - rm2[jj]) * rsqrtf(rv2[jj] + EPSBN) * g2[jj] + be2[jj];
                h2[jj] = fmaxf(p, 0.f);
            }
        }
        __syncthreads();

        for (int r = 0; r < 16; ++r) {
            const int jj = wv * 16 + r;
            float p = W3[(size_t)jj * 64 + lane] * h2[lane];
            #pragma unroll
            for (int off = 32; off; off >>= 1) p += __shfl_xor(p, off);
            if (lane == 0) {
                p += b3[jj];
                coeff_out[s * PCADIM + jj] = p;
                coeff_ws[s * PCADIM + jj]  = p;
            }
        }
    }
}

// ------- kernel 2: {tpose (91 blocks)} || {512B-granule pipelined gather} ----
// Gather block = (sample b, ch-block cb of 64 channels, group g of 6 chunks).
// Wave-load = 64 lanes x float2 from ONE channel row = 512B contiguous.
// LDS channel-major [64][129]: write banks {2l+c}%32 2-way, read (cc+p)%32 2-way.
__global__ __launch_bounds__(256, 4) void k_gather(
    const float* __restrict__ feature,           // [BSAMP, CCH, NPTS]
    const unsigned long long* __restrict__ ws_mask,
    const int* __restrict__ ws_spref,
    const int* __restrict__ ws_count,
    float* __restrict__ gf,                      // [BSAMP, NOUT, CCH]
    const float* __restrict__ coeff_ws,
    const float* __restrict__ comp,
    const float* __restrict__ mean_,
    const float* __restrict__ scale_,
    float* __restrict__ tpose)
{
    __shared__ float lds[CHN * LDSQ];            // 33 KB -> 4 blocks/CU
    __shared__ int   spos[PCH];
    __shared__ int   sel_list[PCH];              // two halves: word0 | word1
    __shared__ int   s_ns[2];

    const int tid = threadIdx.x;

    if (blockIdx.x < K4B) {
        // ---------------- tpose part ----------------
        float* sc = lds;
        for (int o = tid; o < NBATCH * PCADIM; o += 256) sc[o] = coeff_ws[o];
        __syncthreads();

        const int v = blockIdx.x * 256 + tid;
        if (v >= V3) return;

        float acc[NBATCH];
        #pragma unroll
        for (int s = 0; s < NBATCH; ++s) acc[s] = 0.f;
        for (int k = 0; k < PCADIM; ++k) {
            const float pv = comp[(size_t)k * V3 + v];
            #pragma unroll
            for (int s = 0; s < NBATCH; ++s)
                acc[s] = fmaf(sc[s * PCADIM + k], pv, acc[s]);
        }
        const float mn = mean_[v], scl = scale_[v];
        #pragma unroll
        for (int s = 0; s < NBATCH; ++s)
            tpose[(size_t)s * V3 + v] = (acc[s] + mn) * scl;
        return;
    }

    // ---------------- gather part ----------------
    const int gb  = blockIdx.x - K4B;
    const int b   = gb / (CHB * NGRP);
    const int rem = gb % (CHB * NGRP);
    const int cb  = rem / NGRP;
    const int g   = rem % NGRP;

    const int lane = tid & 63;                   // float2 slot -> points 2l, 2l+1
    const int cg   = tid >> 6;                   // 0..3 -> 16 channels each
    const int p0   = lane * 2;
    const float* fbase = feature + ((size_t)b * CCH + cb * CHN) * NPTS;

    float2 rc[16], rn[16];

    // prologue: issue loads for chunk g*CPG
    {
        const int i0 = g * (CPG * PCH);
        const int il = min(PCH, NPTS - i0);
        const float* fb = fbase + i0 + p0;
        if (p0 < il) {
            #pragma unroll
            for (int it = 0; it < 16; ++it)
                rc[it] = *(const float2*)(fb + (size_t)(cg * 16 + it) * NPTS);
        } else {
            #pragma unroll
            for (int it = 0; it < 16; ++it) rc[it] = make_float2(0.f, 0.f);
        }
    }

    // gf tail-zero share issued EARLY (hides under prologue load wait)
    {
        const int cnt  = ws_count[b];
        const int tail = NOUT - cnt;
        if (tail > 0) {
            const int nshares = CHB * NGRP;                    // 18
            const int share = (tail + nshares - 1) / nshares;
            const int idx   = cb * NGRP + g;
            const int r0    = cnt + idx * share;
            const int r1    = min(r0 + share, NOUT);
            const int nrows = r1 - r0;
            if (nrows > 0) {
                float4* base4 = (float4*)(gf + ((size_t)b * NOUT + r0) * CCH);
                const int total = nrows * 32;
                for (int f = tid; f < total; f += 256)
                    base4[f] = make_float4(0.f, 0.f, 0.f, 0.f);
            }
        }
    }

    #pragma unroll
    for (int c = 0; c < CPG; ++c) {
        const int chunk = g * CPG + c;

        // issue next chunk's loads early
        if (c + 1 < CPG) {
            const int i1 = (chunk + 1) * PCH;
            const int il = min(PCH, NPTS - i1);
            const float* fb = fbase + i1 + p0;
            if (p0 < il) {
                #pragma unroll
                for (int it = 0; it < 16; ++it)
                    rn[it] = *(const float2*)(fb + (size_t)(cg * 16 + it) * NPTS);
            } else {
                #pragma unroll
                for (int it = 0; it < 16; ++it) rn[it] = make_float2(0.f, 0.f);
            }
        }

        __syncthreads();                          // LDS free (prev phase B done)

        // LDS write, channel-major (2-way banks, free)
        #pragma unroll
        for (int it = 0; it < 16; ++it) {
            const int cch = cg * 16 + it;
            lds[cch * LDSQ + p0]     = rc[it].x;
            lds[cch * LDSQ + p0 + 1] = rc[it].y;
        }

        // selection for the chunk's two mask words (waves 0 and 1)
        if (tid < 128) {
            const int w    = tid >> 6;            // word half 0/1
            const int word = 2 * chunk + w;
            const unsigned long long m = ws_mask[b * NW + word];
            const int base = ws_spref[b * NW + word];
            const int sel  = (int)((m >> lane) & 1ull);
            const int pos  = base + __popcll(m & ((1ull << lane) - 1ull));
            const int sp   = (sel && pos < NOUT) ? pos : -1;
            spos[tid] = sp;
            const unsigned long long mm = __ballot(sp >= 0);
            const int before = __popcll(mm & ((1ull << lane) - 1ull));
            if (sp >= 0) sel_list[w * 64 + before] = tid;   // local point idx
            if (lane == 0) s_ns[w] = __popcll(mm);
        }
        __syncthreads();

        // phase B: 256B half-row writes, 4 rows per iteration (1 per wave)
        const int rw = tid >> 6;                  // 0..3
        #pragma unroll 1
        for (int w = 0; w < 2; ++w) {
            const int ns = s_ns[w];
            for (int s = rw; s < ns; s += 4) {
                const int p   = sel_list[w * 64 + s];       // 0..127
                const int pos = spos[p];
                gf[((size_t)b * NOUT + pos) * CCH + cb * CHN + lane] =
                    lds[lane * LDSQ + p];
            }
        }

        if (c + 1 < CPG) {
            #pragma unroll
            for (int it = 0; it < 16; ++it) rc[it] = rn[it];
        }
    }
}

// ---------------- launcher ---------------------------------------------------
extern "C" void kernel_launch(void* const* d_in, const int* in_sizes, int n_in,
                              void* d_out, int out_size, void* d_ws, size_t ws_size,
                              hipStream_t stream) {
    const float* x      = (const float*)d_in[0];
    const float* logits = (const float*)d_in[1];
    const float* feat   = (const float*)d_in[2];
    const float* gsum   = (const float*)d_in[3];
    const float* W1  = (const float*)d_in[4];
    const float* b1  = (const float*)d_in[5];
    const float* g1  = (const float*)d_in[6];
    const float* be1 = (const float*)d_in[7];
    const float* rm1 = (const float*)d_in[8];
    const float* rv1 = (const float*)d_in[9];
    const float* W2  = (const float*)d_in[10];
    const float* b2  = (const float*)d_in[11];
    const float* g2  = (const float*)d_in[12];
    const float* be2 = (const float*)d_in[13];
    const float* rm2 = (const float*)d_in[14];
    const float* rv2 = (const float*)d_in[15];
    const float* W3  = (const float*)d_in[16];
    const float* b3  = (const float*)d_in[17];
    const float* comp  = (const float*)d_in[18];
    const float* mean_ = (const float*)d_in[19];
    const float* scale_= (const float*)d_in[20];
    const int* d_label = (const int*)d_in[21];

    float* out   = (float*)d_out;
    float* gv    = out + OFF_GV;
    float* gf    = out + OFF_GF;
    float* coeff = out + OFF_COEFF;
    float* tpose = out + OFF_TPOSE;

    unsigned long long* ws_mask = (unsigned long long*)d_ws;      // 64*108 u64
    int*   ws_spref = (int*)(ws_mask + BSAMP * NW);               // 64*108 int
    int*   ws_count = ws_spref + BSAMP * NW;                      // 64
    float* coeff_ws = (float*)(ws_count + BSAMP);                 // 512

    k_prep  <<<BSAMP + NBATCH,  256, 0, stream>>>(logits, d_label, x, ws_mask, gv,
                                                  ws_spref, ws_count,
                                                  gsum, W1, b1, g1, be1, rm1, rv1,
                                                  W2, b2, g2, be2, rm2, rv2, W3, b3,
                                                  coeff, coeff_ws);
    k_gather<<<K4B + NGATHER,   256, 0, stream>>>(feat, ws_mask, ws_spref, ws_count,
                                                  gf, coeff_ws, comp, mean_, scale_,
                                                  tpose);
}